// Round 6
// baseline (819.459 us; speedup 1.0000x reference)
//
#include <hip/hip_runtime.h>
#include <hip/hip_bf16.h>
#include <cstdint>

#define DIM   2048
#define MROWS 16384  // B*S = 8*2048
#define NH    64     // K halves of 32

typedef __bf16 bf16x8 __attribute__((ext_vector_type(8)));
typedef float  f32x4  __attribute__((ext_vector_type(4)));
typedef unsigned short u16;
typedef unsigned int   u32;

#define BARRIER() asm volatile("s_barrier" ::: "memory")
#define WAITVM(N) asm volatile("s_waitcnt vmcnt(" #N ")" ::: "memory")

// ---- ws layout (bytes), total 160 MiB ----
// [0,         25165824) : ternary bf16 Wf,Wc,Wg   (3 x 2048x2048 x 2B)
// [25165824,  33554432) : ternary bf16 Wo
// [33554432, 100663296) : x cast to bf16          (16384x2048 x 2B)
// [100663296,167772160) : gh = g*h bf16           (16384x2048 x 2B)

__device__ __forceinline__ u16 ternary_bits(float w) {
    u32 u = __float_as_uint(w);
    u16 s = (u16)((u >> 16) & 0x8000u);
    return (__builtin_fabsf(w) < 0.33f) ? (u16)0 : (u16)(0x3F80u | s);
}

__device__ __forceinline__ u16 f2bf_rne(float f) {
    u32 u = __float_as_uint(f);
    u32 r = (u + 0x7FFFu + ((u >> 16) & 1u)) >> 16;
    return (u16)r;
}

__device__ __forceinline__ void gload16(const void* g, void* l) {
    __builtin_amdgcn_global_load_lds(
        (const __attribute__((address_space(1))) void*)g,
        (__attribute__((address_space(3))) void*)l,
        16, 0, 0);
}

// ---------------- prep kernels ----------------

__global__ void prep_weights(const float* __restrict__ wf, const float* __restrict__ wc,
                             const float* __restrict__ wg, const float* __restrict__ wo,
                             u16* __restrict__ out) {
    const float* srcs[4] = {wf, wc, wg, wo};
    const float* src = srcs[blockIdx.y];
    u16* dst = out + (size_t)blockIdx.y * (DIM * DIM);
    int e = (blockIdx.x * 256 + threadIdx.x) * 8;
    float4 v0 = *(const float4*)(src + e);
    float4 v1 = *(const float4*)(src + e + 4);
    ushort4 o0, o1;
    o0.x = ternary_bits(v0.x); o0.y = ternary_bits(v0.y);
    o0.z = ternary_bits(v0.z); o0.w = ternary_bits(v0.w);
    o1.x = ternary_bits(v1.x); o1.y = ternary_bits(v1.y);
    o1.z = ternary_bits(v1.z); o1.w = ternary_bits(v1.w);
    *(ushort4*)(dst + e)     = o0;
    *(ushort4*)(dst + e + 4) = o1;
}

__global__ void cast_x(const float* __restrict__ x, u16* __restrict__ xb) {
    size_t e = ((size_t)blockIdx.x * 256 + threadIdx.x) * 8;
    float4 v0 = *(const float4*)(x + e);
    float4 v1 = *(const float4*)(x + e + 4);
    ushort4 o0, o1;
    o0.x = f2bf_rne(v0.x); o0.y = f2bf_rne(v0.y);
    o0.z = f2bf_rne(v0.z); o0.w = f2bf_rne(v0.w);
    o1.x = f2bf_rne(v1.x); o1.y = f2bf_rne(v1.y);
    o1.z = f2bf_rne(v1.z); o1.w = f2bf_rne(v1.w);
    *(ushort4*)(xb + e)     = o0;
    *(ushort4*)(xb + e + 4) = o1;
}

// ---------------- fused GEMM1 ----------------
// BM=256, BN=128 (x3 gates), K-halves of 32. 512 thr (8 waves 2x4),
// wave tile 128x32 per gate (M_rep=8, N_rep=2). 3-slot LDS ring of 40KB halves
// (A 16KB + 3xB 8KB), prefetch 2 halves ahead, WAITVM(5) counted (never 0 in loop).
// Staging: linear gload_lds dest (tid*16B per pass) + source chunk-XOR; reads
// apply the same involution: LDS(r,c) holds global chunk c ^ ((r>>1)&3).

__global__ __launch_bounds__(512) void gemm1(
    const u16* __restrict__ xb,      // [16384][2048] bf16
    const u16* __restrict__ wt,      // [3][2048][2048] bf16 ternary (f,c,g)
    const float* __restrict__ bfv_, const float* __restrict__ bcv_, const float* __restrict__ bgv_,
    const float* __restrict__ hprev, // [16384][2048] f32
    float* __restrict__ hout,        // f32, second half of d_out
    u16* __restrict__ gh)            // bf16 ws
{
    __shared__ __align__(16) u16 lds[3 * 20480];   // 120 KB: slot = A[8192] + B[3][4096]

    const int tid  = threadIdx.x;
    const int lane = tid & 63;
    const int wave = tid >> 6;
    const int wr   = wave >> 2;   // 0..1 -> 128-row half
    const int wcq  = wave & 3;    // 0..3 -> 32-col quarter

    const int bid  = blockIdx.x;                     // 1024 = 64 m x 16 n
    const int swz  = (bid & 7) * 128 + (bid >> 3);   // XCD-contiguous (2 n-tiles/XCD)
    const int brow = (swz & 63) * 256;
    const int bcol = (swz >> 6) * 128;

    const int srow = tid >> 2;                 // 0..127 (staging row within pass)
    const int gc4  = (tid & 3) ^ ((tid >> 3) & 3);
    const int ldst = tid * 8;                  // u16 offset within 8KB pass

    const int fr  = lane & 15;
    const int hi  = lane >> 4;
    const int csw = (hi ^ ((fr >> 1) & 3)) * 8;

    f32x4 acc0[3][8] = {};
    f32x4 acc1[3][8] = {};

    const u16* aSrc0 = xb + (size_t)(brow + srow) * DIM;
    const u16* aSrc1 = xb + (size_t)(brow + 128 + srow) * DIM;
    const u16* bSrcB = wt + (size_t)(bcol + srow) * DIM;
    const size_t WST = (size_t)DIM * DIM;

    auto issueA = [&](int so, int k0) {
        gload16(aSrc0 + k0 + gc4 * 8, (u16*)&lds[so + ldst]);
        gload16(aSrc1 + k0 + gc4 * 8, (u16*)&lds[so + 4096 + ldst]);
    };
    auto issueB = [&](int so, int k0, int g) {
        gload16(bSrcB + (size_t)g * WST + k0 + gc4 * 8,
                (u16*)&lds[so + 8192 + g * 4096 + ldst]);
    };

    auto rdA = [&](int so, bf16x8 (&a)[8]) {
        #pragma unroll
        for (int mi = 0; mi < 8; ++mi)
            a[mi] = *(const bf16x8*)(&lds[so + (wr * 128 + mi * 16 + fr) * 32 + csw]);
    };
    auto rdB = [&](int so, int ni, bf16x8 (&b)[3]) {
        #pragma unroll
        for (int g = 0; g < 3; ++g)
            b[g] = *(const bf16x8*)(&lds[so + 8192 + g * 4096 + (wcq * 32 + ni * 16 + fr) * 32 + csw]);
    };
    auto domfma = [&](bf16x8 (&a)[8], bf16x8 (&b)[3], f32x4 (&c)[3][8]) {
        __builtin_amdgcn_s_setprio(1);
        #pragma unroll
        for (int g = 0; g < 3; ++g)
            #pragma unroll
            for (int mi = 0; mi < 8; ++mi)
                c[g][mi] = __builtin_amdgcn_mfma_f32_16x16x32_bf16(a[mi], b[g], c[g][mi], 0, 0, 0);
        __builtin_amdgcn_s_setprio(0);
    };

    int so0 = 0, so1 = 20480, so2 = 40960;   // slots for h, h+1, h+2

    // prologue: stage halves 0 and 1 (5 loads each, order A0,A1,B0,B1,B2)
    issueA(so0, 0); issueB(so0, 0, 0); issueB(so0, 0, 1); issueB(so0, 0, 2);
    issueA(so1, 32); issueB(so1, 32, 0); issueB(so1, 32, 1); issueB(so1, 32, 2);
    WAITVM(5);       // retire half 0
    BARRIER();

    bf16x8 a[8], b[3];
    #pragma unroll 1
    for (int h = 0; h < NH - 2; ++h) {
        const int kn = (h + 2) * 32;
        // p0 (ni0)
        rdA(so0, a); rdB(so0, 0, b);
        issueA(so2, kn); issueB(so2, kn, 0);
        BARRIER();
        domfma(a, b, acc0);
        BARRIER();
        // p1 (ni1)
        rdB(so0, 1, b);
        issueB(so2, kn, 1); issueB(so2, kn, 2);
        WAITVM(5);   // retire half h+1 (outstanding: (h+1):5 + (h+2):5)
        BARRIER();
        domfma(a, b, acc1);
        BARRIER();
        int t = so0; so0 = so1; so1 = so2; so2 = t;
    }
    // h = NH-2: no issues; retire last half
    rdA(so0, a); rdB(so0, 0, b);
    BARRIER(); domfma(a, b, acc0); BARRIER();
    rdB(so0, 1, b);
    WAITVM(0);
    BARRIER(); domfma(a, b, acc1); BARRIER();
    { int t = so0; so0 = so1; so1 = so2; so2 = t; }
    // h = NH-1: all data resident
    rdA(so0, a); rdB(so0, 0, b);
    domfma(a, b, acc0);
    rdB(so0, 1, b);
    domfma(a, b, acc1);

    // fused epilogue: f=sigmoid, c=silu, g=sigmoid, h=f*hp+(1-f)*c, gh=g*h
    auto epi = [&](int ni, f32x4 (&c)[3][8]) {
        const int col = bcol + wcq * 32 + ni * 16 + fr;
        const float bfv = bfv_[col], bcv = bcv_[col], bgv = bgv_[col];
        #pragma unroll
        for (int mi = 0; mi < 8; ++mi) {
            #pragma unroll
            for (int j = 0; j < 4; ++j) {
                const int row = brow + wr * 128 + mi * 16 + hi * 4 + j;
                const size_t idx = (size_t)row * DIM + col;
                float pf = c[0][mi][j] + bfv;
                float pc = c[1][mi][j] + bcv;
                float pg = c[2][mi][j] + bgv;
                float f  = 1.f / (1.f + __expf(-pf));
                float cc = pc / (1.f + __expf(-pc));
                float g  = 1.f / (1.f + __expf(-pg));
                float hh = f * hprev[idx] + (1.f - f) * cc;
                hout[idx] = hh;
                gh[idx] = f2bf_rne(g * hh);
            }
        }
    };
    epi(0, acc0);
    epi(1, acc1);
}

// ---------------- GEMM2: o = gh @ Wo^T + bo ----------------
// BM=256, BN=256, K-halves of 32. 512 thr (8 waves 2x4), wave tile 128x64
// (M_rep=8, N_rep=4). 3-slot ring of 32KB halves (A 16KB + B 16KB), WAITVM(4).

__global__ __launch_bounds__(512) void gemm2(
    const u16* __restrict__ gh,    // [16384][2048] bf16
    const u16* __restrict__ wot,   // [2048][2048] bf16 ternary
    const float* __restrict__ bov_,
    float* __restrict__ oout)      // f32, first half of d_out
{
    __shared__ __align__(16) u16 lds[3 * 16384];   // 96 KB: slot = A[8192] + B[8192]

    const int tid  = threadIdx.x;
    const int lane = tid & 63;
    const int wave = tid >> 6;
    const int wr   = wave >> 2;   // 0..1 -> 128-row half
    const int wcq  = wave & 3;    // 0..3 -> 64-col quarter

    const int bid  = blockIdx.x;                   // 512 = 64 m x 8 n
    const int swz  = (bid & 7) * 64 + (bid >> 3);  // one n-column per XCD
    const int brow = (swz & 63) * 256;
    const int bcol = (swz >> 6) * 256;

    const int srow = tid >> 2;
    const int gc4  = (tid & 3) ^ ((tid >> 3) & 3);
    const int ldst = tid * 8;

    const int fr  = lane & 15;
    const int hi  = lane >> 4;
    const int csw = (hi ^ ((fr >> 1) & 3)) * 8;

    f32x4 accL[8][2] = {};   // ni 0..1
    f32x4 accH[8][2] = {};   // ni 2..3

    const u16* aSrc0 = gh  + (size_t)(brow + srow) * DIM;
    const u16* aSrc1 = gh  + (size_t)(brow + 128 + srow) * DIM;
    const u16* bSrc0 = wot + (size_t)(bcol + srow) * DIM;
    const u16* bSrc1 = wot + (size_t)(bcol + 128 + srow) * DIM;

    auto issueA = [&](int so, int k0) {
        gload16(aSrc0 + k0 + gc4 * 8, (u16*)&lds[so + ldst]);
        gload16(aSrc1 + k0 + gc4 * 8, (u16*)&lds[so + 4096 + ldst]);
    };
    auto issueB = [&](int so, int k0) {
        gload16(bSrc0 + k0 + gc4 * 8, (u16*)&lds[so + 8192 + ldst]);
        gload16(bSrc1 + k0 + gc4 * 8, (u16*)&lds[so + 12288 + ldst]);
    };

    auto rdA = [&](int so, bf16x8 (&a)[8]) {
        #pragma unroll
        for (int mi = 0; mi < 8; ++mi)
            a[mi] = *(const bf16x8*)(&lds[so + (wr * 128 + mi * 16 + fr) * 32 + csw]);
    };
    auto rdB2 = [&](int so, int nbase, bf16x8 (&b)[2]) {
        #pragma unroll
        for (int jn = 0; jn < 2; ++jn)
            b[jn] = *(const bf16x8*)(&lds[so + 8192 + (wcq * 64 + (nbase + jn) * 16 + fr) * 32 + csw]);
    };
    auto domfma2 = [&](bf16x8 (&a)[8], bf16x8 (&b)[2], f32x4 (&c)[8][2]) {
        __builtin_amdgcn_s_setprio(1);
        #pragma unroll
        for (int jn = 0; jn < 2; ++jn)
            #pragma unroll
            for (int mi = 0; mi < 8; ++mi)
                c[mi][jn] = __builtin_amdgcn_mfma_f32_16x16x32_bf16(a[mi], b[jn], c[mi][jn], 0, 0, 0);
        __builtin_amdgcn_s_setprio(0);
    };

    int so0 = 0, so1 = 16384, so2 = 32768;

    // prologue: halves 0,1 (4 loads each: A0,A1,B0,B1)
    issueA(so0, 0); issueB(so0, 0);
    issueA(so1, 32); issueB(so1, 32);
    WAITVM(4);
    BARRIER();

    bf16x8 a[8], b[2];
    #pragma unroll 1
    for (int h = 0; h < NH - 2; ++h) {
        const int kn = (h + 2) * 32;
        // p0 (ni 0-1)
        rdA(so0, a); rdB2(so0, 0, b);
        issueA(so2, kn);
        BARRIER();
        domfma2(a, b, accL);
        BARRIER();
        // p1 (ni 2-3)
        rdB2(so0, 2, b);
        issueB(so2, kn);
        WAITVM(4);
        BARRIER();
        domfma2(a, b, accH);
        BARRIER();
        int t = so0; so0 = so1; so1 = so2; so2 = t;
    }
    // h = NH-2
    rdA(so0, a); rdB2(so0, 0, b);
    BARRIER(); domfma2(a, b, accL); BARRIER();
    rdB2(so0, 2, b);
    WAITVM(0);
    BARRIER(); domfma2(a, b, accH); BARRIER();
    { int t = so0; so0 = so1; so1 = so2; so2 = t; }
    // h = NH-1
    rdA(so0, a); rdB2(so0, 0, b);
    domfma2(a, b, accL);
    rdB2(so0, 2, b);
    domfma2(a, b, accH);

    auto epi2 = [&](int nbase, f32x4 (&c)[8][2]) {
        #pragma unroll
        for (int jn = 0; jn < 2; ++jn) {
            const int col = bcol + wcq * 64 + (nbase + jn) * 16 + fr;
            const float bov = bov_[col];
            #pragma unroll
            for (int mi = 0; mi < 8; ++mi)
                #pragma unroll
                for (int j = 0; j < 4; ++j)
                    oout[(size_t)(brow + wr * 128 + mi * 16 + hi * 4 + j) * DIM + col] = c[mi][jn][j] + bov;
        }
    };
    epi2(0, accL);
    epi2(2, accH);
}

extern "C" void kernel_launch(void* const* d_in, const int* in_sizes, int n_in,
                              void* d_out, int out_size, void* d_ws, size_t ws_size,
                              hipStream_t stream) {
    const float* x  = (const float*)d_in[0];
    const float* hp = (const float*)d_in[1];
    const float* wf = (const float*)d_in[2];
    const float* bf = (const float*)d_in[3];
    const float* wc = (const float*)d_in[4];
    const float* bc = (const float*)d_in[5];
    const float* wg = (const float*)d_in[6];
    const float* bg = (const float*)d_in[7];
    const float* wo = (const float*)d_in[8];
    const float* bo = (const float*)d_in[9];

    float* o_out = (float*)d_out;
    float* h_out = o_out + (size_t)MROWS * DIM;

    u16* w_t  = (u16*)d_ws;                              // wf,wc,wg then wo
    u16* x_bf = (u16*)((char*)d_ws + 33554432);
    u16* gh   = (u16*)((char*)d_ws + 100663296);

    prep_weights<<<dim3(2048, 4), 256, 0, stream>>>(wf, wc, wg, wo, w_t);
    cast_x<<<dim3(16384), 256, 0, stream>>>(x, x_bf);
    gemm1<<<dim3(1024), 512, 0, stream>>>(x_bf, w_t, bf, bc, bg, hp, h_out, gh);
    gemm2<<<dim3(512), 512, 0, stream>>>(gh, w_t + 3 * (size_t)DIM * DIM, bo, o_out);
}

// Round 7
// 722.099 us; speedup vs baseline: 1.1348x; 1.1348x over previous
//
#include <hip/hip_runtime.h>
#include <hip/hip_bf16.h>
#include <cstdint>

#define DIM   2048
#define MROWS 16384  // B*S = 8*2048
#define NH    64     // K halves of 32

typedef __bf16 bf16x8 __attribute__((ext_vector_type(8)));
typedef float  f32x4  __attribute__((ext_vector_type(4)));
typedef unsigned short u16;
typedef unsigned int   u32;

#define BARRIER() asm volatile("s_barrier" ::: "memory")
#define WAITVM(N) asm volatile("s_waitcnt vmcnt(" #N ")" ::: "memory")

// ---- ws layout (bytes), total 160 MiB ----
// [0,         25165824) : ternary bf16 Wf,Wc,Wg   (3 x 2048x2048 x 2B)
// [25165824,  33554432) : ternary bf16 Wo
// [33554432, 100663296) : x cast to bf16          (16384x2048 x 2B)
// [100663296,167772160) : gh = g*h bf16           (16384x2048 x 2B)

__device__ __forceinline__ u16 ternary_bits(float w) {
    u32 u = __float_as_uint(w);
    u16 s = (u16)((u >> 16) & 0x8000u);
    return (__builtin_fabsf(w) < 0.33f) ? (u16)0 : (u16)(0x3F80u | s);
}

__device__ __forceinline__ u16 f2bf_rne(float f) {
    u32 u = __float_as_uint(f);
    u32 r = (u + 0x7FFFu + ((u >> 16) & 1u)) >> 16;
    return (u16)r;
}

__device__ __forceinline__ void gload16(const void* g, void* l) {
    __builtin_amdgcn_global_load_lds(
        (const __attribute__((address_space(1))) void*)g,
        (__attribute__((address_space(3))) void*)l,
        16, 0, 0);
}

// ---------------- prep kernels ----------------

__global__ void prep_weights(const float* __restrict__ wf, const float* __restrict__ wc,
                             const float* __restrict__ wg, const float* __restrict__ wo,
                             u16* __restrict__ out) {
    const float* srcs[4] = {wf, wc, wg, wo};
    const float* src = srcs[blockIdx.y];
    u16* dst = out + (size_t)blockIdx.y * (DIM * DIM);
    int e = (blockIdx.x * 256 + threadIdx.x) * 8;
    float4 v0 = *(const float4*)(src + e);
    float4 v1 = *(const float4*)(src + e + 4);
    ushort4 o0, o1;
    o0.x = ternary_bits(v0.x); o0.y = ternary_bits(v0.y);
    o0.z = ternary_bits(v0.z); o0.w = ternary_bits(v0.w);
    o1.x = ternary_bits(v1.x); o1.y = ternary_bits(v1.y);
    o1.z = ternary_bits(v1.z); o1.w = ternary_bits(v1.w);
    *(ushort4*)(dst + e)     = o0;
    *(ushort4*)(dst + e + 4) = o1;
}

__global__ void cast_x(const float* __restrict__ x, u16* __restrict__ xb) {
    size_t e = ((size_t)blockIdx.x * 256 + threadIdx.x) * 8;
    float4 v0 = *(const float4*)(x + e);
    float4 v1 = *(const float4*)(x + e + 4);
    ushort4 o0, o1;
    o0.x = f2bf_rne(v0.x); o0.y = f2bf_rne(v0.y);
    o0.z = f2bf_rne(v0.z); o0.w = f2bf_rne(v0.w);
    o1.x = f2bf_rne(v1.x); o1.y = f2bf_rne(v1.y);
    o1.z = f2bf_rne(v1.z); o1.w = f2bf_rne(v1.w);
    *(ushort4*)(xb + e)     = o0;
    *(ushort4*)(xb + e + 4) = o1;
}

// ---------------- fused GEMM1: f/c/g preacts + activations + h + gh ----------------
// BM=128, BN=128 (x3 gates), 512 thr (8 waves 2x4), wave tile 64x32 per gate.
// 4-slot LDS ring of k32 halves (slot = A 8KB + 3xB 8KB = 32KB, 128KB total).
// One phase per k32: issue half j+3 (4 gloads), 10 ds_reads of slot j,
// WAITVM(8) (retires half j+1 for next step), barrier, 24 MFMA, barrier.
// Prefetch depth 3 halves (12 outstanding loads). Staging: linear gload_lds dest
// (tid*16B) + source chunk-XOR; reads apply the same involution (R5-verified).

__global__ __launch_bounds__(512) void gemm1(
    const u16* __restrict__ xb,      // [16384][2048] bf16
    const u16* __restrict__ wt,      // [3][2048][2048] bf16 ternary (f,c,g)
    const float* __restrict__ bfv_, const float* __restrict__ bcv_, const float* __restrict__ bgv_,
    const float* __restrict__ hprev, // [16384][2048] f32
    float* __restrict__ hout,        // f32, second half of d_out
    u16* __restrict__ gh)            // bf16 ws
{
    __shared__ __align__(16) u16 lds[4][16384];   // 4 x 32KB slots

    const int tid  = threadIdx.x;
    const int lane = tid & 63;
    const int wave = tid >> 6;
    const int wr   = wave >> 2;   // 0..1
    const int wcq  = wave & 3;    // 0..3

    const int bid  = blockIdx.x;                     // 2048 = 128 m x 16 n
    const int swz  = (bid & 7) * 256 + (bid >> 3);   // XCD-contiguous chunks
    const int brow = (swz & 127) * 128;
    const int bcol = (swz >> 7) * 128;

    const int row512 = tid >> 2;                      // 0..127
    const int gc4    = (tid & 3) ^ ((tid >> 3) & 3);  // swizzled source chunk
    const int ldst   = tid * 8;                       // u16 offset in 8KB pass

    const int fr  = lane & 15;
    const int hi  = lane >> 4;                        // 0..3
    const int csw = (hi ^ ((fr >> 1) & 3)) * 8;       // swizzled read chunk (u16)

    f32x4 acc0[3][4] = {};   // ni = 0
    f32x4 acc1[3][4] = {};   // ni = 1

    const u16* aSrc  = xb + (size_t)(brow + row512) * DIM;
    const u16* bSrc0 = wt + (size_t)(bcol + row512) * DIM;
    const size_t WST = (size_t)DIM * DIM;

    auto issueHalf = [&](int slot, int k0) {
        gload16(aSrc + k0 + gc4 * 8,                (u16*)&lds[slot][ldst]);
        gload16(bSrc0 + 0 * WST + k0 + gc4 * 8,     (u16*)&lds[slot][4096  + ldst]);
        gload16(bSrc0 + 1 * WST + k0 + gc4 * 8,     (u16*)&lds[slot][8192  + ldst]);
        gload16(bSrc0 + 2 * WST + k0 + gc4 * 8,     (u16*)&lds[slot][12288 + ldst]);
    };

    auto rdFrags = [&](const u16* sl, bf16x8 (&a)[4], bf16x8 (&b0)[3], bf16x8 (&b1)[3]) {
        #pragma unroll
        for (int mi = 0; mi < 4; ++mi)
            a[mi] = *(const bf16x8*)(sl + (wr * 64 + mi * 16 + fr) * 32 + csw);
        #pragma unroll
        for (int g = 0; g < 3; ++g)
            b0[g] = *(const bf16x8*)(sl + 4096 + g * 4096 + (wcq * 32 + fr) * 32 + csw);
        #pragma unroll
        for (int g = 0; g < 3; ++g)
            b1[g] = *(const bf16x8*)(sl + 4096 + g * 4096 + (wcq * 32 + 16 + fr) * 32 + csw);
    };

    auto cluster = [&](bf16x8 (&a)[4], bf16x8 (&b0)[3], bf16x8 (&b1)[3]) {
        __builtin_amdgcn_s_setprio(1);
        #pragma unroll
        for (int g = 0; g < 3; ++g)
            #pragma unroll
            for (int mi = 0; mi < 4; ++mi)
                acc0[g][mi] = __builtin_amdgcn_mfma_f32_16x16x32_bf16(a[mi], b0[g], acc0[g][mi], 0, 0, 0);
        #pragma unroll
        for (int g = 0; g < 3; ++g)
            #pragma unroll
            for (int mi = 0; mi < 4; ++mi)
                acc1[g][mi] = __builtin_amdgcn_mfma_f32_16x16x32_bf16(a[mi], b1[g], acc1[g][mi], 0, 0, 0);
        __builtin_amdgcn_s_setprio(0);
    };

    // prologue: stage halves 0,1,2 (12 loads); retire half 0
    issueHalf(0, 0); issueHalf(1, 32); issueHalf(2, 64);
    WAITVM(8);
    BARRIER();

    bf16x8 a[4], b0[3], b1[3];
    #pragma unroll 1
    for (int j = 0; j < NH - 3; ++j) {
        const u16* sl = &lds[j & 3][0];
        issueHalf((j + 3) & 3, (j + 3) * 32);   // outstanding: j+1, j+2, j+3 (12)
        rdFrags(sl, a, b0, b1);
        WAITVM(8);                              // retire half j+1
        BARRIER();
        cluster(a, b0, b1);
        BARRIER();
    }
    // j = NH-3 (slot 1): outstanding 62,63 (8) -> retire 62
    rdFrags(&lds[(NH - 3) & 3][0], a, b0, b1);
    WAITVM(4);
    BARRIER();
    cluster(a, b0, b1);
    BARRIER();
    // j = NH-2 (slot 2): outstanding 63 (4) -> retire all
    rdFrags(&lds[(NH - 2) & 3][0], a, b0, b1);
    WAITVM(0);
    BARRIER();
    cluster(a, b0, b1);
    BARRIER();
    // j = NH-1 (slot 3): all resident
    rdFrags(&lds[(NH - 1) & 3][0], a, b0, b1);
    cluster(a, b0, b1);

    // fused epilogue: f=sigmoid, c=silu, g=sigmoid, h=f*hp+(1-f)*c, gh=g*h
    auto epi = [&](int ni, f32x4 (&c)[3][4]) {
        const int col = bcol + wcq * 32 + ni * 16 + fr;
        const float bfv = bfv_[col], bcv = bcv_[col], bgv = bgv_[col];
        #pragma unroll
        for (int mi = 0; mi < 4; ++mi) {
            #pragma unroll
            for (int j = 0; j < 4; ++j) {
                const int row = brow + wr * 64 + mi * 16 + hi * 4 + j;
                const size_t idx = (size_t)row * DIM + col;
                float pf = c[0][mi][j] + bfv;
                float pc = c[1][mi][j] + bcv;
                float pg = c[2][mi][j] + bgv;
                float f  = 1.f / (1.f + __expf(-pf));
                float cc = pc / (1.f + __expf(-pc));
                float g  = 1.f / (1.f + __expf(-pg));
                float hh = f * hprev[idx] + (1.f - f) * cc;
                hout[idx] = hh;
                gh[idx] = f2bf_rne(g * hh);
            }
        }
    };
    epi(0, acc0);
    epi(1, acc1);
}

// ---------------- GEMM2: o = gh @ Wo^T + bo ----------------
// BM=256, BN=256, K-halves of 32. 512 thr (8 waves 2x4), wave tile 128x64
// (M_rep=8, N_rep=4). 3-slot ring of 32KB halves (A 16KB + B 16KB), WAITVM(4).
// (unchanged from R6 — it improved there; isolating gemm1's change this round)

__global__ __launch_bounds__(512) void gemm2(
    const u16* __restrict__ gh,    // [16384][2048] bf16
    const u16* __restrict__ wot,   // [2048][2048] bf16 ternary
    const float* __restrict__ bov_,
    float* __restrict__ oout)      // f32, first half of d_out
{
    __shared__ __align__(16) u16 lds[3 * 16384];   // 96 KB: slot = A[8192] + B[8192]

    const int tid  = threadIdx.x;
    const int lane = tid & 63;
    const int wave = tid >> 6;
    const int wr   = wave >> 2;   // 0..1 -> 128-row half
    const int wcq  = wave & 3;    // 0..3 -> 64-col quarter

    const int bid  = blockIdx.x;                   // 512 = 64 m x 8 n
    const int swz  = (bid & 7) * 64 + (bid >> 3);  // one n-column per XCD
    const int brow = (swz & 63) * 256;
    const int bcol = (swz >> 6) * 256;

    const int srow = tid >> 2;
    const int gc4  = (tid & 3) ^ ((tid >> 3) & 3);
    const int ldst = tid * 8;

    const int fr  = lane & 15;
    const int hi  = lane >> 4;
    const int csw = (hi ^ ((fr >> 1) & 3)) * 8;

    f32x4 accL[8][2] = {};   // ni 0..1
    f32x4 accH[8][2] = {};   // ni 2..3

    const u16* aSrc0 = gh  + (size_t)(brow + srow) * DIM;
    const u16* aSrc1 = gh  + (size_t)(brow + 128 + srow) * DIM;
    const u16* bSrc0 = wot + (size_t)(bcol + srow) * DIM;
    const u16* bSrc1 = wot + (size_t)(bcol + 128 + srow) * DIM;

    auto issueA = [&](int so, int k0) {
        gload16(aSrc0 + k0 + gc4 * 8, (u16*)&lds[so + ldst]);
        gload16(aSrc1 + k0 + gc4 * 8, (u16*)&lds[so + 4096 + ldst]);
    };
    auto issueB = [&](int so, int k0) {
        gload16(bSrc0 + k0 + gc4 * 8, (u16*)&lds[so + 8192 + ldst]);
        gload16(bSrc1 + k0 + gc4 * 8, (u16*)&lds[so + 12288 + ldst]);
    };

    auto rdA = [&](int so, bf16x8 (&a)[8]) {
        #pragma unroll
        for (int mi = 0; mi < 8; ++mi)
            a[mi] = *(const bf16x8*)(&lds[so + (wr * 128 + mi * 16 + fr) * 32 + csw]);
    };
    auto rdB2 = [&](int so, int nbase, bf16x8 (&b)[2]) {
        #pragma unroll
        for (int jn = 0; jn < 2; ++jn)
            b[jn] = *(const bf16x8*)(&lds[so + 8192 + (wcq * 64 + (nbase + jn) * 16 + fr) * 32 + csw]);
    };
    auto domfma2 = [&](bf16x8 (&a)[8], bf16x8 (&b)[2], f32x4 (&c)[8][2]) {
        __builtin_amdgcn_s_setprio(1);
        #pragma unroll
        for (int jn = 0; jn < 2; ++jn)
            #pragma unroll
            for (int mi = 0; mi < 8; ++mi)
                c[mi][jn] = __builtin_amdgcn_mfma_f32_16x16x32_bf16(a[mi], b[jn], c[mi][jn], 0, 0, 0);
        __builtin_amdgcn_s_setprio(0);
    };

    int so0 = 0, so1 = 16384, so2 = 32768;

    // prologue: halves 0,1 (4 loads each: A0,A1,B0,B1)
    issueA(so0, 0); issueB(so0, 0);
    issueA(so1, 32); issueB(so1, 32);
    WAITVM(4);
    BARRIER();

    bf16x8 a[8], b[2];
    #pragma unroll 1
    for (int h = 0; h < NH - 2; ++h) {
        const int kn = (h + 2) * 32;
        // p0 (ni 0-1)
        rdA(so0, a); rdB2(so0, 0, b);
        issueA(so2, kn);
        BARRIER();
        domfma2(a, b, accL);
        BARRIER();
        // p1 (ni 2-3)
        rdB2(so0, 2, b);
        issueB(so2, kn);
        WAITVM(4);
        BARRIER();
        domfma2(a, b, accH);
        BARRIER();
        int t = so0; so0 = so1; so1 = so2; so2 = t;
    }
    // h = NH-2
    rdA(so0, a); rdB2(so0, 0, b);
    BARRIER(); domfma2(a, b, accL); BARRIER();
    rdB2(so0, 2, b);
    WAITVM(0);
    BARRIER(); domfma2(a, b, accH); BARRIER();
    { int t = so0; so0 = so1; so1 = so2; so2 = t; }
    // h = NH-1
    rdA(so0, a); rdB2(so0, 0, b);
    domfma2(a, b, accL);
    rdB2(so0, 2, b);
    domfma2(a, b, accH);

    auto epi2 = [&](int nbase, f32x4 (&c)[8][2]) {
        #pragma unroll
        for (int jn = 0; jn < 2; ++jn) {
            const int col = bcol + wcq * 64 + (nbase + jn) * 16 + fr;
            const float bov = bov_[col];
            #pragma unroll
            for (int mi = 0; mi < 8; ++mi)
                #pragma unroll
                for (int j = 0; j < 4; ++j)
                    oout[(size_t)(brow + wr * 128 + mi * 16 + hi * 4 + j) * DIM + col] = c[mi][jn][j] + bov;
        }
    };
    epi2(0, accL);
    epi2(2, accH);
}

extern "C" void kernel_launch(void* const* d_in, const int* in_sizes, int n_in,
                              void* d_out, int out_size, void* d_ws, size_t ws_size,
                              hipStream_t stream) {
    const float* x  = (const float*)d_in[0];
    const float* hp = (const float*)d_in[1];
    const float* wf = (const float*)d_in[2];
    const float* bf = (const float*)d_in[3];
    const float* wc = (const float*)d_in[4];
    const float* bc = (const float*)d_in[5];
    const float* wg = (const float*)d_in[6];
    const float* bg = (const float*)d_in[7];
    const float* wo = (const float*)d_in[8];
    const float* bo = (const float*)d_in[9];

    float* o_out = (float*)d_out;
    float* h_out = o_out + (size_t)MROWS * DIM;

    u16* w_t  = (u16*)d_ws;                              // wf,wc,wg then wo
    u16* x_bf = (u16*)((char*)d_ws + 33554432);
    u16* gh   = (u16*)((char*)d_ws + 100663296);

    prep_weights<<<dim3(2048, 4), 256, 0, stream>>>(wf, wc, wg, wo, w_t);
    cast_x<<<dim3(16384), 256, 0, stream>>>(x, x_bf);
    gemm1<<<dim3(2048), 512, 0, stream>>>(x_bf, w_t, bf, bc, bg, hp, h_out, gh);
    gemm2<<<dim3(512), 512, 0, stream>>>(gh, w_t + 3 * (size_t)DIM * DIM, bo, o_out);
}

// Round 8
// 715.087 us; speedup vs baseline: 1.1460x; 1.0098x over previous
//
#include <hip/hip_runtime.h>
#include <hip/hip_bf16.h>
#include <cstdint>

#define DIM   2048
#define MROWS 16384  // B*S = 8*2048
#define NH    64     // K halves of 32

typedef __bf16 bf16x8 __attribute__((ext_vector_type(8)));
typedef float  f32x4  __attribute__((ext_vector_type(4)));
typedef unsigned short u16;
typedef unsigned int   u32;

#define BARRIER() asm volatile("s_barrier" ::: "memory")
#define WAITVM(N) asm volatile("s_waitcnt vmcnt(" #N ")" ::: "memory")

// ---- ws layout (bytes), total 160 MiB ----
// [0,         25165824) : ternary bf16 Wf,Wc,Wg   (3 x 2048x2048 x 2B)
// [25165824,  33554432) : ternary bf16 Wo
// [33554432, 100663296) : x cast to bf16          (16384x2048 x 2B)
// [100663296,167772160) : gh = g*h bf16           (16384x2048 x 2B)

__device__ __forceinline__ u16 ternary_bits(float w) {
    u32 u = __float_as_uint(w);
    u16 s = (u16)((u >> 16) & 0x8000u);
    return (__builtin_fabsf(w) < 0.33f) ? (u16)0 : (u16)(0x3F80u | s);
}

__device__ __forceinline__ u16 f2bf_rne(float f) {
    u32 u = __float_as_uint(f);
    u32 r = (u + 0x7FFFu + ((u >> 16) & 1u)) >> 16;
    return (u16)r;
}

__device__ __forceinline__ void gload16(const void* g, void* l) {
    __builtin_amdgcn_global_load_lds(
        (const __attribute__((address_space(1))) void*)g,
        (__attribute__((address_space(3))) void*)l,
        16, 0, 0);
}

// ---------------- prep kernels ----------------

__global__ void prep_weights(const float* __restrict__ wf, const float* __restrict__ wc,
                             const float* __restrict__ wg, const float* __restrict__ wo,
                             u16* __restrict__ out) {
    const float* srcs[4] = {wf, wc, wg, wo};
    const float* src = srcs[blockIdx.y];
    u16* dst = out + (size_t)blockIdx.y * (DIM * DIM);
    int e = (blockIdx.x * 256 + threadIdx.x) * 8;
    float4 v0 = *(const float4*)(src + e);
    float4 v1 = *(const float4*)(src + e + 4);
    ushort4 o0, o1;
    o0.x = ternary_bits(v0.x); o0.y = ternary_bits(v0.y);
    o0.z = ternary_bits(v0.z); o0.w = ternary_bits(v0.w);
    o1.x = ternary_bits(v1.x); o1.y = ternary_bits(v1.y);
    o1.z = ternary_bits(v1.z); o1.w = ternary_bits(v1.w);
    *(ushort4*)(dst + e)     = o0;
    *(ushort4*)(dst + e + 4) = o1;
}

__global__ void cast_x(const float* __restrict__ x, u16* __restrict__ xb) {
    size_t e = ((size_t)blockIdx.x * 256 + threadIdx.x) * 8;
    float4 v0 = *(const float4*)(x + e);
    float4 v1 = *(const float4*)(x + e + 4);
    ushort4 o0, o1;
    o0.x = f2bf_rne(v0.x); o0.y = f2bf_rne(v0.y);
    o0.z = f2bf_rne(v0.z); o0.w = f2bf_rne(v0.w);
    o1.x = f2bf_rne(v1.x); o1.y = f2bf_rne(v1.y);
    o1.z = f2bf_rne(v1.z); o1.w = f2bf_rne(v1.w);
    *(ushort4*)(xb + e)     = o0;
    *(ushort4*)(xb + e + 4) = o1;
}

// ---------------- fused GEMM1: f/c/g preacts + activations + h + gh ----------------
// BM=128, BN=128 (x3 gates), 512 thr (8 waves 2x4), wave tile 64x32 per gate.
// 4-slot LDS ring of k32 halves (slot = A 8KB + 3xB 8KB = 32KB, 128KB total).
// Read-ahead 2-subphase schedule per k32 j:
//   P0: ds_read b1(j) + issue gloads(j+3)  -> MFMA0 (a(j) x b0(j), read last phase)
//   P1: WAITVM(8) (retire j+1) + BARRIER -> ds_read a(j+1),b0(j+1) -> MFMA1 (a(j) x b1(j)) -> BARRIER
// so ds_reads are always in flight UNDER an MFMA cluster (T3 interleave).
// Staging: linear gload_lds dest (tid*16B) + source chunk-XOR; reads apply the
// same involution (R5-verified, conflicts measured 0).

__global__ __launch_bounds__(512) void gemm1(
    const u16* __restrict__ xb,      // [16384][2048] bf16
    const u16* __restrict__ wt,      // [3][2048][2048] bf16 ternary (f,c,g)
    const float* __restrict__ bfv_, const float* __restrict__ bcv_, const float* __restrict__ bgv_,
    const float* __restrict__ hprev, // [16384][2048] f32
    float* __restrict__ hout,        // f32, second half of d_out
    u16* __restrict__ gh)            // bf16 ws
{
    __shared__ __align__(16) u16 lds[4][16384];   // 4 x 32KB slots

    const int tid  = threadIdx.x;
    const int lane = tid & 63;
    const int wave = tid >> 6;
    const int wr   = wave >> 2;   // 0..1
    const int wcq  = wave & 3;    // 0..3

    const int bid  = blockIdx.x;                     // 2048 = 128 m x 16 n
    const int swz  = (bid & 7) * 256 + (bid >> 3);   // XCD-contiguous chunks
    const int brow = (swz & 127) * 128;
    const int bcol = (swz >> 7) * 128;

    const int row512 = tid >> 2;                      // 0..127
    const int gc4    = (tid & 3) ^ ((tid >> 3) & 3);  // swizzled source chunk
    const int ldst   = tid * 8;                       // u16 offset in 8KB pass

    const int fr  = lane & 15;
    const int hi  = lane >> 4;                        // 0..3
    const int csw = (hi ^ ((fr >> 1) & 3)) * 8;       // swizzled read chunk (u16)

    f32x4 acc0[3][4] = {};   // ni = 0
    f32x4 acc1[3][4] = {};   // ni = 1

    const u16* aSrc  = xb + (size_t)(brow + row512) * DIM;
    const u16* bSrc0 = wt + (size_t)(bcol + row512) * DIM;
    const size_t WST = (size_t)DIM * DIM;

    auto issueHalf = [&](int slot, int k0) {
        gload16(aSrc + k0 + gc4 * 8,            (u16*)&lds[slot][ldst]);
        gload16(bSrc0 + 0 * WST + k0 + gc4 * 8, (u16*)&lds[slot][4096  + ldst]);
        gload16(bSrc0 + 1 * WST + k0 + gc4 * 8, (u16*)&lds[slot][8192  + ldst]);
        gload16(bSrc0 + 2 * WST + k0 + gc4 * 8, (u16*)&lds[slot][12288 + ldst]);
    };

    auto rdA = [&](const u16* sl, bf16x8 (&a)[4]) {
        #pragma unroll
        for (int mi = 0; mi < 4; ++mi)
            a[mi] = *(const bf16x8*)(sl + (wr * 64 + mi * 16 + fr) * 32 + csw);
    };
    auto rdB0 = [&](const u16* sl, bf16x8 (&b)[3]) {
        #pragma unroll
        for (int g = 0; g < 3; ++g)
            b[g] = *(const bf16x8*)(sl + 4096 + g * 4096 + (wcq * 32 + fr) * 32 + csw);
    };
    auto rdB1 = [&](const u16* sl, bf16x8 (&b)[3]) {
        #pragma unroll
        for (int g = 0; g < 3; ++g)
            b[g] = *(const bf16x8*)(sl + 4096 + g * 4096 + (wcq * 32 + 16 + fr) * 32 + csw);
    };
    auto mfmaC = [&](bf16x8 (&a)[4], bf16x8 (&b)[3], f32x4 (&c)[3][4]) {
        __builtin_amdgcn_s_setprio(1);
        #pragma unroll
        for (int g = 0; g < 3; ++g)
            #pragma unroll
            for (int mi = 0; mi < 4; ++mi)
                c[g][mi] = __builtin_amdgcn_mfma_f32_16x16x32_bf16(a[mi], b[g], c[g][mi], 0, 0, 0);
        __builtin_amdgcn_s_setprio(0);
    };

    bf16x8 aP[4], b0P[3], aQ[4], b0Q[3], b1[3];

    // prologue: stage halves 0,1,2; retire h0; read a(0),b0(0)
    issueHalf(0, 0); issueHalf(1, 32); issueHalf(2, 64);
    WAITVM(8);
    BARRIER();
    rdA(&lds[0][0], aP); rdB0(&lds[0][0], b0P);

    // steady step: current frags aC/b0C for half j; reads next into aN/b0N
    auto step = [&](int j, bf16x8 (&aC)[4], bf16x8 (&b0C)[3],
                    bf16x8 (&aN)[4], bf16x8 (&b0N)[3]) {
        const u16* sl  = &lds[j & 3][0];
        const u16* sln = &lds[(j + 1) & 3][0];
        // P0
        rdB1(sl, b1);
        issueHalf((j + 3) & 3, (j + 3) * 32);   // outstanding: j+1,j+2,j+3 = 12
        mfmaC(aC, b0C, acc0);
        // P1
        WAITVM(8);                              // retire half j+1
        BARRIER();
        rdA(sln, aN); rdB0(sln, b0N);
        mfmaC(aC, b1, acc1);
        BARRIER();
    };

    #pragma unroll 1
    for (int j = 0; j < NH - 4; j += 2) {       // j = 0..58 (30 pairs -> ends at P)
        step(j,     aP, b0P, aQ, b0Q);
        step(j + 1, aQ, b0Q, aP, b0P);
    }
    step(NH - 4, aP, b0P, aQ, b0Q);             // j=60, issues half 63

    { // j = NH-3 (61): no issue; outstanding {62,63}=8 -> WAITVM(4)
        const u16* sl  = &lds[(NH - 3) & 3][0];
        const u16* sln = &lds[(NH - 2) & 3][0];
        rdB1(sl, b1);
        mfmaC(aQ, b0Q, acc0);
        WAITVM(4);
        BARRIER();
        rdA(sln, aP); rdB0(sln, b0P);
        mfmaC(aQ, b1, acc1);
        BARRIER();
    }
    { // j = NH-2 (62): outstanding {63}=4 -> WAITVM(0)
        const u16* sl  = &lds[(NH - 2) & 3][0];
        const u16* sln = &lds[(NH - 1) & 3][0];
        rdB1(sl, b1);
        mfmaC(aP, b0P, acc0);
        WAITVM(0);
        BARRIER();
        rdA(sln, aQ); rdB0(sln, b0Q);
        mfmaC(aP, b1, acc1);
        BARRIER();
    }
    { // j = NH-1 (63): all resident
        const u16* sl = &lds[(NH - 1) & 3][0];
        rdB1(sl, b1);
        mfmaC(aQ, b0Q, acc0);
        mfmaC(aQ, b1, acc1);
    }

    // fused epilogue: f=sigmoid, c=silu, g=sigmoid, h=f*hp+(1-f)*c, gh=g*h
    auto epi = [&](int ni, f32x4 (&c)[3][4]) {
        const int col = bcol + wcq * 32 + ni * 16 + fr;
        const float bfv = bfv_[col], bcv = bcv_[col], bgv = bgv_[col];
        #pragma unroll
        for (int mi = 0; mi < 4; ++mi) {
            #pragma unroll
            for (int j = 0; j < 4; ++j) {
                const int row = brow + wr * 64 + mi * 16 + hi * 4 + j;
                const size_t idx = (size_t)row * DIM + col;
                float pf = c[0][mi][j] + bfv;
                float pc = c[1][mi][j] + bcv;
                float pg = c[2][mi][j] + bgv;
                float f  = 1.f / (1.f + __expf(-pf));
                float cc = pc / (1.f + __expf(-pc));
                float g  = 1.f / (1.f + __expf(-pg));
                float hh = f * hprev[idx] + (1.f - f) * cc;
                hout[idx] = hh;
                gh[idx] = f2bf_rne(g * hh);
            }
        }
    };
    epi(0, acc0);
    epi(1, acc1);
}

// ---------------- GEMM2: o = gh @ Wo^T + bo ----------------
// BM=256, BN=256, K-halves of 32. 512 thr (8 waves 2x4), wave tile 128x64
// (M_rep=8, N_rep=4). 3-slot ring (96 KB), read-ahead 2-subphase schedule:
//   P0: rd bH(h) + issue A(h+2) -> MFMA(accL)
//   P1: WAITVM(2) + BARRIER -> rd a(h+1),bL(h+1) + issue B(h+2) -> MFMA(accH) -> BARRIER

__global__ __launch_bounds__(512) void gemm2(
    const u16* __restrict__ gh,    // [16384][2048] bf16
    const u16* __restrict__ wot,   // [2048][2048] bf16 ternary
    const float* __restrict__ bov_,
    float* __restrict__ oout)      // f32, first half of d_out
{
    __shared__ __align__(16) u16 lds[3 * 16384];   // 96 KB: slot = A[8192] + B[8192]

    const int tid  = threadIdx.x;
    const int lane = tid & 63;
    const int wave = tid >> 6;
    const int wr   = wave >> 2;   // 0..1 -> 128-row half
    const int wcq  = wave & 3;    // 0..3 -> 64-col quarter

    const int bid  = blockIdx.x;                   // 512 = 64 m x 8 n
    const int swz  = (bid & 7) * 64 + (bid >> 3);  // one n-column per XCD
    const int brow = (swz & 63) * 256;
    const int bcol = (swz >> 6) * 256;

    const int srow = tid >> 2;
    const int gc4  = (tid & 3) ^ ((tid >> 3) & 3);
    const int ldst = tid * 8;

    const int fr  = lane & 15;
    const int hi  = lane >> 4;
    const int csw = (hi ^ ((fr >> 1) & 3)) * 8;

    f32x4 accL[8][2] = {};   // ni 0..1
    f32x4 accH[8][2] = {};   // ni 2..3

    const u16* aSrc0 = gh  + (size_t)(brow + srow) * DIM;
    const u16* aSrc1 = gh  + (size_t)(brow + 128 + srow) * DIM;
    const u16* bSrc0 = wot + (size_t)(bcol + srow) * DIM;
    const u16* bSrc1 = wot + (size_t)(bcol + 128 + srow) * DIM;

    auto issueA = [&](int so, int k0) {
        gload16(aSrc0 + k0 + gc4 * 8, (u16*)&lds[so + ldst]);
        gload16(aSrc1 + k0 + gc4 * 8, (u16*)&lds[so + 4096 + ldst]);
    };
    auto issueB = [&](int so, int k0) {
        gload16(bSrc0 + k0 + gc4 * 8, (u16*)&lds[so + 8192 + ldst]);
        gload16(bSrc1 + k0 + gc4 * 8, (u16*)&lds[so + 12288 + ldst]);
    };

    auto rdA = [&](int so, bf16x8 (&a)[8]) {
        #pragma unroll
        for (int mi = 0; mi < 8; ++mi)
            a[mi] = *(const bf16x8*)(&lds[so + (wr * 128 + mi * 16 + fr) * 32 + csw]);
    };
    auto rdBL = [&](int so, bf16x8 (&b)[2]) {
        #pragma unroll
        for (int jn = 0; jn < 2; ++jn)
            b[jn] = *(const bf16x8*)(&lds[so + 8192 + (wcq * 64 + jn * 16 + fr) * 32 + csw]);
    };
    auto rdBH = [&](int so, bf16x8 (&b)[2]) {
        #pragma unroll
        for (int jn = 0; jn < 2; ++jn)
            b[jn] = *(const bf16x8*)(&lds[so + 8192 + (wcq * 64 + (2 + jn) * 16 + fr) * 32 + csw]);
    };
    auto mfma2 = [&](bf16x8 (&a)[8], bf16x8 (&b)[2], f32x4 (&c)[8][2]) {
        __builtin_amdgcn_s_setprio(1);
        #pragma unroll
        for (int jn = 0; jn < 2; ++jn)
            #pragma unroll
            for (int mi = 0; mi < 8; ++mi)
                c[mi][jn] = __builtin_amdgcn_mfma_f32_16x16x32_bf16(a[mi], b[jn], c[mi][jn], 0, 0, 0);
        __builtin_amdgcn_s_setprio(0);
    };

    int so0 = 0, so1 = 16384, so2 = 32768;

    bf16x8 aP[8], bLP[2], aQ[8], bLQ[2], bH[2];

    // prologue: halves 0,1; retire h0; read a(0), bL(0)
    issueA(so0, 0); issueB(so0, 0);
    issueA(so1, 32); issueB(so1, 32);
    WAITVM(4);
    BARRIER();
    rdA(so0, aP); rdBL(so0, bLP);

    auto step = [&](int h, bf16x8 (&aC)[8], bf16x8 (&bLC)[2],
                    bf16x8 (&aN)[8], bf16x8 (&bLN)[2]) {
        const int kn = (h + 2) * 32;
        // P0
        rdBH(so0, bH);
        issueA(so2, kn);                 // outstanding: A(h+1),B(h+1),A(h+2) = 6
        mfma2(aC, bLC, accL);
        // P1
        WAITVM(2);                       // retire half h+1
        BARRIER();
        rdA(so1, aN); rdBL(so1, bLN);
        issueB(so2, kn);                 // outstanding: A(h+2),B(h+2) = 4
        mfma2(aC, bH, accH);
        BARRIER();
        int t = so0; so0 = so1; so1 = so2; so2 = t;
    };

    #pragma unroll 1
    for (int h = 0; h < NH - 2; h += 2) {   // h = 0..61 (31 pairs -> ends at P)
        step(h,     aP, bLP, aQ, bLQ);
        step(h + 1, aQ, bLQ, aP, bLP);
    }
    { // h = NH-2 (62): no issue; outstanding {A63,B63}=4 -> WAITVM(0)
        rdBH(so0, bH);
        mfma2(aP, bLP, accL);
        WAITVM(0);
        BARRIER();
        rdA(so1, aQ); rdBL(so1, bLQ);
        mfma2(aP, bH, accH);
        BARRIER();
        int t = so0; so0 = so1; so1 = so2; so2 = t;
    }
    { // h = NH-1 (63): all resident
        rdBH(so0, bH);
        mfma2(aQ, bLQ, accL);
        mfma2(aQ, bH, accH);
    }

    auto epi2 = [&](int nbase, f32x4 (&c)[8][2]) {
        #pragma unroll
        for (int jn = 0; jn < 2; ++jn) {
            const int col = bcol + wcq * 64 + (nbase + jn) * 16 + fr;
            const float bov = bov_[col];
            #pragma unroll
            for (int mi = 0; mi < 8; ++mi)
                #pragma unroll
                for (int j = 0; j < 4; ++j)
                    oout[(size_t)(brow + wr * 128 + mi * 16 + hi * 4 + j) * DIM + col] = c[mi][jn][j] + bov;
        }
    };
    epi2(0, accL);
    epi2(2, accH);
}

extern "C" void kernel_launch(void* const* d_in, const int* in_sizes, int n_in,
                              void* d_out, int out_size, void* d_ws, size_t ws_size,
                              hipStream_t stream) {
    const float* x  = (const float*)d_in[0];
    const float* hp = (const float*)d_in[1];
    const float* wf = (const float*)d_in[2];
    const float* bf = (const float*)d_in[3];
    const float* wc = (const float*)d_in[4];
    const float* bc = (const float*)d_in[5];
    const float* wg = (const float*)d_in[6];
    const float* bg = (const float*)d_in[7];
    const float* wo = (const float*)d_in[8];
    const float* bo = (const float*)d_in[9];

    float* o_out = (float*)d_out;
    float* h_out = o_out + (size_t)MROWS * DIM;

    u16* w_t  = (u16*)d_ws;                              // wf,wc,wg then wo
    u16* x_bf = (u16*)((char*)d_ws + 33554432);
    u16* gh   = (u16*)((char*)d_ws + 100663296);

    prep_weights<<<dim3(2048, 4), 256, 0, stream>>>(wf, wc, wg, wo, w_t);
    cast_x<<<dim3(16384), 256, 0, stream>>>(x, x_bf);
    gemm1<<<dim3(2048), 512, 0, stream>>>(x_bf, w_t, bf, bc, bg, hp, h_out, gh);
    gemm2<<<dim3(512), 512, 0, stream>>>(gh, w_t + 3 * (size_t)DIM * DIM, bo, o_out);
}